// Round 4
// baseline (110.132 us; speedup 1.0000x reference)
//
#include <hip/hip_runtime.h>
#include <math.h>

// Problem constants (from reference)
#define B_DIM 16
#define T_DIM 2048
#define D_DIM 4096
#define G_DIM 8
#define GS    512
#define H_DIM 16
#define CHUNKS 128          // t-chunks per b (16 rows each)
#define NPARTIAL (B_DIM * G_DIM * CHUNKS)   // 16384 doubles

// Output layout (float32, concatenated flat in return order)
#define OUT_DBITS   0        // [16,8]   = 128
#define OUT_GIDX    128      // [16,4096]= 65536
#define OUT_EMB     65664    // [16,8,512] = 65536
#define OUT_BLOSS   131200   // scalar
#define OUT_DIV     131201   // scalar
#define OUT_BPROBS  131202   // [16,8] = 128

// ---------------------------------------------------------------------------
// Kernel 1: reduce importance_scores [B,T,D] -> per-(b,g,chunk) partials.
// Each block streams a CONTIGUOUS 256 KB slab (one b, 16 t-rows, full D) and
// produces all 8 group sums. A row (4096 f) is covered in 4 phases of
// 256 float4; thread's group for phase p is 2p + (tid>>7) — constant per
// wave, so accumulators are statically indexed and reduced by shuffles.
// ---------------------------------------------------------------------------
__global__ __launch_bounds__(256) void k_reduce(const float* __restrict__ scores,
                                                double* __restrict__ partials) {
    const int bid   = blockIdx.x;        // [0, 2048)
    const int b     = bid >> 7;
    const int chunk = bid & 127;
    const int tid   = threadIdx.x;

    const float4* base = reinterpret_cast<const float4*>(
        scores + (size_t)b * T_DIM * D_DIM + (size_t)chunk * 16 * D_DIM);

    double a0 = 0.0, a1 = 0.0, a2 = 0.0, a3 = 0.0;
    #pragma unroll 4
    for (int r = 0; r < 16; ++r) {
        const float4* row = base + (size_t)r * (D_DIM / 4);
        const float4 v0 = row[tid];
        const float4 v1 = row[tid + 256];
        const float4 v2 = row[tid + 512];
        const float4 v3 = row[tid + 768];
        a0 += (double)v0.x + (double)v0.y + (double)v0.z + (double)v0.w;
        a1 += (double)v1.x + (double)v1.y + (double)v1.z + (double)v1.w;
        a2 += (double)v2.x + (double)v2.y + (double)v2.z + (double)v2.w;
        a3 += (double)v3.x + (double)v3.y + (double)v3.z + (double)v3.w;
    }

    // Per-wave reduce: within a wave, group of phase p is g = 2p + (wave>>1).
    const int lane = tid & 63;
    const int wave = tid >> 6;
    __shared__ double wsum[4][4];        // [wave][phase]
    double acc[4] = {a0, a1, a2, a3};
    #pragma unroll
    for (int p = 0; p < 4; ++p) {
        double v = acc[p];
        #pragma unroll
        for (int off = 32; off > 0; off >>= 1) v += __shfl_down(v, off, 64);
        if (lane == 0) wsum[wave][p] = v;
    }
    __syncthreads();

    if (tid < G_DIM) {
        // group g: phase p = g>>1, waves w0 = 2*(g&1), w0+1
        const int p  = tid >> 1;
        const int w0 = (tid & 1) * 2;
        partials[(size_t)(b * G_DIM + tid) * CHUNKS + chunk] = wsum[w0][p] + wsum[w0 + 1][p];
    }
}

// ---------------------------------------------------------------------------
// Kernel 2: finish group means, run the tiny MLP + gumbel softmax + alloc +
// discretize; write discrete_bits, bit_probs, scalars; stash bit_w in ws.
// ---------------------------------------------------------------------------
__global__ __launch_bounds__(128) void k_mlp(const double* __restrict__ partials,
                                             const float* __restrict__ u,
                                             const float* __restrict__ W1,
                                             const float* __restrict__ b1,
                                             const float* __restrict__ ln_g,
                                             const float* __restrict__ ln_b,
                                             const float* __restrict__ W2,
                                             const float* __restrict__ b2,
                                             float* __restrict__ out,
                                             float* __restrict__ bitw) {
    __shared__ float gi[B_DIM * G_DIM];   // group_imp [16][8]
    __shared__ float ent[B_DIM];
    __shared__ float bitsum[B_DIM];
    const int tid = threadIdx.x;

    if (tid < 128) {
        double s = 0.0;
        #pragma unroll
        for (int c = 0; c < CHUNKS; ++c) s += partials[(size_t)tid * CHUNKS + c];
        gi[tid] = (float)(s * (1.0 / ((double)T_DIM * (double)GS)));
    }
    __syncthreads();

    if (tid < B_DIM) {
        const int b = tid;
        // h = GELU(group_imp @ W1 + b1)   (exact gelu: 0.5x(1+erf(x/sqrt2)))
        float h[H_DIM];
        #pragma unroll
        for (int i = 0; i < H_DIM; ++i) {
            float a = b1[i];
            #pragma unroll
            for (int g = 0; g < G_DIM; ++g) a += gi[b * G_DIM + g] * W1[g * H_DIM + i];
            h[i] = 0.5f * a * (1.0f + erff(a * 0.70710678118654752440f));
        }
        // LayerNorm over H
        float mu = 0.f;
        #pragma unroll
        for (int i = 0; i < H_DIM; ++i) mu += h[i];
        mu *= (1.0f / (float)H_DIM);
        float var = 0.f;
        #pragma unroll
        for (int i = 0; i < H_DIM; ++i) { float d = h[i] - mu; var += d * d; }
        var *= (1.0f / (float)H_DIM);
        const float inv = rsqrtf(var + 1e-5f);
        #pragma unroll
        for (int i = 0; i < H_DIM; ++i) h[i] = (h[i] - mu) * inv * ln_g[i] + ln_b[i];

        // logits + gumbel
        float z[G_DIM];
        #pragma unroll
        for (int j = 0; j < G_DIM; ++j) {
            float a = b2[j];
            #pragma unroll
            for (int i = 0; i < H_DIM; ++i) a += h[i] * W2[i * G_DIM + j];
            const float uu = u[b * G_DIM + j];
            const float gum = -logf(-logf(uu + 1e-8f) + 1e-8f);
            z[j] = a + gum;
        }
        // softmax over 8
        float m = z[0];
        #pragma unroll
        for (int j = 1; j < G_DIM; ++j) m = fmaxf(m, z[j]);
        float p[G_DIM]; float ssum = 0.f;
        #pragma unroll
        for (int j = 0; j < G_DIM; ++j) { p[j] = expf(z[j] - m); ssum += p[j]; }
        const float rs = 1.0f / ssum;

        // alloc, budget rescale, clip
        float alloc[G_DIM]; float asum = 0.f;
        #pragma unroll
        for (int j = 0; j < G_DIM; ++j) {
            p[j] *= rs;
            alloc[j] = 2.0f + p[j] * 6.0f;
            asum += alloc[j];
        }
        const float scale = 32.0f / asum;   // budget = 4 * 8

        float entb = 0.f, bs = 0.f;
        #pragma unroll
        for (int j = 0; j < G_DIM; ++j) {
            float a = alloc[j] * scale;
            a = fminf(fmaxf(a, 2.0f), 8.0f);
            // nearest of {2,4,8}; argmin tie-break -> lower index
            const float hard = (a <= 3.0f) ? 2.0f : ((a <= 6.0f) ? 4.0f : 8.0f);
            out[OUT_DBITS + b * G_DIM + j]  = hard;
            out[OUT_BPROBS + b * G_DIM + j] = p[j];
            entb += p[j] * logf(p[j] + 1e-8f);
            bs += hard;
            // bit_w = softmax(exp(-|hard - levels|)) over 3 levels
            const float x0 = expf(-fabsf(hard - 2.0f));
            const float x1 = expf(-fabsf(hard - 4.0f));
            const float x2 = expf(-fabsf(hard - 8.0f));
            const float mm = fmaxf(x0, fmaxf(x1, x2));
            const float e0 = expf(x0 - mm), e1 = expf(x1 - mm), e2 = expf(x2 - mm);
            const float ir = 1.0f / (e0 + e1 + e2);
            bitw[(b * G_DIM + j) * 3 + 0] = e0 * ir;
            bitw[(b * G_DIM + j) * 3 + 1] = e1 * ir;
            bitw[(b * G_DIM + j) * 3 + 2] = e2 * ir;
        }
        ent[b] = entb;
        bitsum[b] = bs;
    }
    __syncthreads();

    if (tid == 0) {
        float tb = 0.f, te = 0.f;
        #pragma unroll
        for (int b = 0; b < B_DIM; ++b) { tb += bitsum[b]; te += ent[b]; }
        const float mb = tb * (1.0f / (float)(B_DIM * G_DIM));
        out[OUT_BLOSS] = (mb - 4.0f) * (mb - 4.0f);
        out[OUT_DIV]   = -te * (1.0f / (float)B_DIM);
    }
}

// ---------------------------------------------------------------------------
// Kernel 3: embeddings = bit_w @ bit_embeddings, plus constant group_indices.
// One float4 of each per thread; 64 blocks x 256 threads = 16384 float4.
// ---------------------------------------------------------------------------
__global__ __launch_bounds__(256) void k_emb(const float* __restrict__ bitw,
                                             const float* __restrict__ emb,
                                             float* __restrict__ out) {
    const int l = blockIdx.x * 256 + threadIdx.x;   // [0,16384)
    const int b   = l >> 10;        // 4096/4 float4 per batch row
    const int rem = l & 1023;
    const int g   = rem >> 7;       // 512/4 float4 per group
    const int j4  = rem & 127;

    const float4* e4 = reinterpret_cast<const float4*>(emb);  // [3][128]
    const float4 e0 = e4[0 * 128 + j4];
    const float4 e1 = e4[1 * 128 + j4];
    const float4 e2 = e4[2 * 128 + j4];
    const float w0 = bitw[(b * G_DIM + g) * 3 + 0];
    const float w1 = bitw[(b * G_DIM + g) * 3 + 1];
    const float w2 = bitw[(b * G_DIM + g) * 3 + 2];

    float4 r;
    r.x = w0 * e0.x + w1 * e1.x + w2 * e2.x;
    r.y = w0 * e0.y + w1 * e1.y + w2 * e2.y;
    r.z = w0 * e0.z + w1 * e1.z + w2 * e2.z;
    r.w = w0 * e0.w + w1 * e1.w + w2 * e2.w;

    float4* o4 = reinterpret_cast<float4*>(out);
    o4[(OUT_EMB / 4) + l] = r;

    const float gv = (float)g;                   // d // 512, same for all 4 lanes of the float4
    o4[(OUT_GIDX / 4) + l] = make_float4(gv, gv, gv, gv);
}

// ---------------------------------------------------------------------------
extern "C" void kernel_launch(void* const* d_in, const int* in_sizes, int n_in,
                              void* d_out, int out_size, void* d_ws, size_t ws_size,
                              hipStream_t stream) {
    const float* scores = (const float*)d_in[0];
    const float* u      = (const float*)d_in[1];
    const float* W1     = (const float*)d_in[2];
    const float* b1     = (const float*)d_in[3];
    const float* ln_g   = (const float*)d_in[4];
    const float* ln_b   = (const float*)d_in[5];
    const float* W2     = (const float*)d_in[6];
    const float* b2     = (const float*)d_in[7];
    const float* emb    = (const float*)d_in[8];
    float* out = (float*)d_out;

    double* partials = (double*)d_ws;                                     // 16384 * 8 B
    float*  bitw     = (float*)((char*)d_ws + NPARTIAL * sizeof(double)); // 384 * 4 B

    k_reduce<<<B_DIM * CHUNKS, 256, 0, stream>>>(scores, partials);
    k_mlp<<<1, 128, 0, stream>>>(partials, u, W1, b1, ln_g, ln_b, W2, b2, out, bitw);
    k_emb<<<64, 256, 0, stream>>>(bitw, emb, out);
}

// Round 5
// 110.080 us; speedup vs baseline: 1.0005x; 1.0005x over previous
//
#include <hip/hip_runtime.h>
#include <math.h>

// Problem constants (from reference)
#define B_DIM 16
#define T_DIM 2048
#define D_DIM 4096
#define G_DIM 8
#define GS    512
#define H_DIM 16
#define CHUNKS 128          // t-chunks per b (16 rows each)
#define NPARTIAL (B_DIM * G_DIM * CHUNKS)   // 16384 doubles

// Output layout (float32, concatenated flat in return order)
#define OUT_DBITS   0        // [16,8]   = 128
#define OUT_GIDX    128      // [16,4096]= 65536
#define OUT_EMB     65664    // [16,8,512] = 65536
#define OUT_BLOSS   131200   // scalar
#define OUT_DIV     131201   // scalar
#define OUT_BPROBS  131202   // [16,8] = 128

// ---------------------------------------------------------------------------
// Kernel 1: reduce importance_scores [B,T,D] -> per-(b,g,chunk) partials.
// Each block streams a CONTIGUOUS 256 KB slab (one b, 16 t-rows, full D) and
// produces all 8 group sums. A row (4096 f) is covered in 4 phases of
// 256 float4; thread's group for phase p is 2p + (tid>>7) — constant per
// wave, so accumulators are statically indexed and reduced by shuffles.
// ---------------------------------------------------------------------------
__global__ __launch_bounds__(256) void k_reduce(const float* __restrict__ scores,
                                                double* __restrict__ partials) {
    const int bid   = blockIdx.x;        // [0, 2048)
    const int b     = bid >> 7;
    const int chunk = bid & 127;
    const int tid   = threadIdx.x;

    const float4* base = reinterpret_cast<const float4*>(
        scores + (size_t)b * T_DIM * D_DIM + (size_t)chunk * 16 * D_DIM);

    double a0 = 0.0, a1 = 0.0, a2 = 0.0, a3 = 0.0;
    #pragma unroll 4
    for (int r = 0; r < 16; ++r) {
        const float4* row = base + (size_t)r * (D_DIM / 4);
        const float4 v0 = row[tid];
        const float4 v1 = row[tid + 256];
        const float4 v2 = row[tid + 512];
        const float4 v3 = row[tid + 768];
        a0 += (double)v0.x + (double)v0.y + (double)v0.z + (double)v0.w;
        a1 += (double)v1.x + (double)v1.y + (double)v1.z + (double)v1.w;
        a2 += (double)v2.x + (double)v2.y + (double)v2.z + (double)v2.w;
        a3 += (double)v3.x + (double)v3.y + (double)v3.z + (double)v3.w;
    }

    // Per-wave reduce: within a wave, group of phase p is g = 2p + (wave>>1).
    const int lane = tid & 63;
    const int wave = tid >> 6;
    __shared__ double wsum[4][4];        // [wave][phase]
    double acc[4] = {a0, a1, a2, a3};
    #pragma unroll
    for (int p = 0; p < 4; ++p) {
        double v = acc[p];
        #pragma unroll
        for (int off = 32; off > 0; off >>= 1) v += __shfl_down(v, off, 64);
        if (lane == 0) wsum[wave][p] = v;
    }
    __syncthreads();

    if (tid < G_DIM) {
        // group g: phase p = g>>1, waves w0 = 2*(g&1), w0+1
        const int p  = tid >> 1;
        const int w0 = (tid & 1) * 2;
        partials[(size_t)(b * G_DIM + tid) * CHUNKS + chunk] = wsum[w0][p] + wsum[w0 + 1][p];
    }
}

// ---------------------------------------------------------------------------
// Kernel 2: finish group means, run the tiny MLP + gumbel softmax + alloc +
// discretize; write discrete_bits, bit_probs, scalars; stash bit_w in ws.
// ---------------------------------------------------------------------------
__global__ __launch_bounds__(128) void k_mlp(const double* __restrict__ partials,
                                             const float* __restrict__ u,
                                             const float* __restrict__ W1,
                                             const float* __restrict__ b1,
                                             const float* __restrict__ ln_g,
                                             const float* __restrict__ ln_b,
                                             const float* __restrict__ W2,
                                             const float* __restrict__ b2,
                                             float* __restrict__ out,
                                             float* __restrict__ bitw) {
    __shared__ float gi[B_DIM * G_DIM];   // group_imp [16][8]
    __shared__ float ent[B_DIM];
    __shared__ float bitsum[B_DIM];
    const int tid = threadIdx.x;

    if (tid < 128) {
        double s = 0.0;
        #pragma unroll
        for (int c = 0; c < CHUNKS; ++c) s += partials[(size_t)tid * CHUNKS + c];
        gi[tid] = (float)(s * (1.0 / ((double)T_DIM * (double)GS)));
    }
    __syncthreads();

    if (tid < B_DIM) {
        const int b = tid;
        // h = GELU(group_imp @ W1 + b1)   (exact gelu: 0.5x(1+erf(x/sqrt2)))
        float h[H_DIM];
        #pragma unroll
        for (int i = 0; i < H_DIM; ++i) {
            float a = b1[i];
            #pragma unroll
            for (int g = 0; g < G_DIM; ++g) a += gi[b * G_DIM + g] * W1[g * H_DIM + i];
            h[i] = 0.5f * a * (1.0f + erff(a * 0.70710678118654752440f));
        }
        // LayerNorm over H
        float mu = 0.f;
        #pragma unroll
        for (int i = 0; i < H_DIM; ++i) mu += h[i];
        mu *= (1.0f / (float)H_DIM);
        float var = 0.f;
        #pragma unroll
        for (int i = 0; i < H_DIM; ++i) { float d = h[i] - mu; var += d * d; }
        var *= (1.0f / (float)H_DIM);
        const float inv = rsqrtf(var + 1e-5f);
        #pragma unroll
        for (int i = 0; i < H_DIM; ++i) h[i] = (h[i] - mu) * inv * ln_g[i] + ln_b[i];

        // logits + gumbel
        float z[G_DIM];
        #pragma unroll
        for (int j = 0; j < G_DIM; ++j) {
            float a = b2[j];
            #pragma unroll
            for (int i = 0; i < H_DIM; ++i) a += h[i] * W2[i * G_DIM + j];
            const float uu = u[b * G_DIM + j];
            const float gum = -logf(-logf(uu + 1e-8f) + 1e-8f);
            z[j] = a + gum;
        }
        // softmax over 8
        float m = z[0];
        #pragma unroll
        for (int j = 1; j < G_DIM; ++j) m = fmaxf(m, z[j]);
        float p[G_DIM]; float ssum = 0.f;
        #pragma unroll
        for (int j = 0; j < G_DIM; ++j) { p[j] = expf(z[j] - m); ssum += p[j]; }
        const float rs = 1.0f / ssum;

        // alloc, budget rescale, clip
        float alloc[G_DIM]; float asum = 0.f;
        #pragma unroll
        for (int j = 0; j < G_DIM; ++j) {
            p[j] *= rs;
            alloc[j] = 2.0f + p[j] * 6.0f;
            asum += alloc[j];
        }
        const float scale = 32.0f / asum;   // budget = 4 * 8

        float entb = 0.f, bs = 0.f;
        #pragma unroll
        for (int j = 0; j < G_DIM; ++j) {
            float a = alloc[j] * scale;
            a = fminf(fmaxf(a, 2.0f), 8.0f);
            // nearest of {2,4,8}; argmin tie-break -> lower index
            const float hard = (a <= 3.0f) ? 2.0f : ((a <= 6.0f) ? 4.0f : 8.0f);
            out[OUT_DBITS + b * G_DIM + j]  = hard;
            out[OUT_BPROBS + b * G_DIM + j] = p[j];
            entb += p[j] * logf(p[j] + 1e-8f);
            bs += hard;
            // bit_w = softmax(exp(-|hard - levels|)) over 3 levels
            const float x0 = expf(-fabsf(hard - 2.0f));
            const float x1 = expf(-fabsf(hard - 4.0f));
            const float x2 = expf(-fabsf(hard - 8.0f));
            const float mm = fmaxf(x0, fmaxf(x1, x2));
            const float e0 = expf(x0 - mm), e1 = expf(x1 - mm), e2 = expf(x2 - mm);
            const float ir = 1.0f / (e0 + e1 + e2);
            bitw[(b * G_DIM + j) * 3 + 0] = e0 * ir;
            bitw[(b * G_DIM + j) * 3 + 1] = e1 * ir;
            bitw[(b * G_DIM + j) * 3 + 2] = e2 * ir;
        }
        ent[b] = entb;
        bitsum[b] = bs;
    }
    __syncthreads();

    if (tid == 0) {
        float tb = 0.f, te = 0.f;
        #pragma unroll
        for (int b = 0; b < B_DIM; ++b) { tb += bitsum[b]; te += ent[b]; }
        const float mb = tb * (1.0f / (float)(B_DIM * G_DIM));
        out[OUT_BLOSS] = (mb - 4.0f) * (mb - 4.0f);
        out[OUT_DIV]   = -te * (1.0f / (float)B_DIM);
    }
}

// ---------------------------------------------------------------------------
// Kernel 3: embeddings = bit_w @ bit_embeddings, plus constant group_indices.
// One float4 of each per thread; 64 blocks x 256 threads = 16384 float4.
// ---------------------------------------------------------------------------
__global__ __launch_bounds__(256) void k_emb(const float* __restrict__ bitw,
                                             const float* __restrict__ emb,
                                             float* __restrict__ out) {
    const int l = blockIdx.x * 256 + threadIdx.x;   // [0,16384)
    const int b   = l >> 10;        // 4096/4 float4 per batch row
    const int rem = l & 1023;
    const int g   = rem >> 7;       // 512/4 float4 per group
    const int j4  = rem & 127;

    const float4* e4 = reinterpret_cast<const float4*>(emb);  // [3][128]
    const float4 e0 = e4[0 * 128 + j4];
    const float4 e1 = e4[1 * 128 + j4];
    const float4 e2 = e4[2 * 128 + j4];
    const float w0 = bitw[(b * G_DIM + g) * 3 + 0];
    const float w1 = bitw[(b * G_DIM + g) * 3 + 1];
    const float w2 = bitw[(b * G_DIM + g) * 3 + 2];

    float4 r;
    r.x = w0 * e0.x + w1 * e1.x + w2 * e2.x;
    r.y = w0 * e0.y + w1 * e1.y + w2 * e2.y;
    r.z = w0 * e0.z + w1 * e1.z + w2 * e2.z;
    r.w = w0 * e0.w + w1 * e1.w + w2 * e2.w;

    float4* o4 = reinterpret_cast<float4*>(out);
    o4[(OUT_EMB / 4) + l] = r;

    const float gv = (float)g;                   // d // 512, same for all 4 lanes of the float4
    o4[(OUT_GIDX / 4) + l] = make_float4(gv, gv, gv, gv);
}

// ---------------------------------------------------------------------------
extern "C" void kernel_launch(void* const* d_in, const int* in_sizes, int n_in,
                              void* d_out, int out_size, void* d_ws, size_t ws_size,
                              hipStream_t stream) {
    const float* scores = (const float*)d_in[0];
    const float* u      = (const float*)d_in[1];
    const float* W1     = (const float*)d_in[2];
    const float* b1     = (const float*)d_in[3];
    const float* ln_g   = (const float*)d_in[4];
    const float* ln_b   = (const float*)d_in[5];
    const float* W2     = (const float*)d_in[6];
    const float* b2     = (const float*)d_in[7];
    const float* emb    = (const float*)d_in[8];
    float* out = (float*)d_out;

    double* partials = (double*)d_ws;                                     // 16384 * 8 B
    float*  bitw     = (float*)((char*)d_ws + NPARTIAL * sizeof(double)); // 384 * 4 B

    k_reduce<<<B_DIM * CHUNKS, 256, 0, stream>>>(scores, partials);
    k_mlp<<<1, 128, 0, stream>>>(partials, u, W1, b1, ln_g, ln_b, W2, b2, out, bitw);
    k_emb<<<64, 256, 0, stream>>>(bitw, emb, out);
}

// Round 6
// 94.897 us; speedup vs baseline: 1.1605x; 1.1600x over previous
//
#include <hip/hip_runtime.h>
#include <math.h>

// Problem constants (from reference)
#define B_DIM 16
#define T_DIM 2048
#define D_DIM 4096
#define G_DIM 8
#define GS    512
#define H_DIM 16
#define CHUNKS 128          // t-chunks per b (16 rows each)
#define NPARTIAL (B_DIM * G_DIM * CHUNKS)   // 16384 doubles

// Output layout (float32, concatenated flat in return order)
#define OUT_DBITS   0        // [16,8]   = 128
#define OUT_GIDX    128      // [16,4096]= 65536
#define OUT_EMB     65664    // [16,8,512] = 65536
#define OUT_BLOSS   131200   // scalar
#define OUT_DIV     131201   // scalar
#define OUT_BPROBS  131202   // [16,8] = 128

typedef float f32x4 __attribute__((ext_vector_type(4)));

// ---------------------------------------------------------------------------
// Kernel 1: reduce importance_scores [B,T,D] -> per-(b,g,chunk) partials.
// Contiguous 256 KB slab per block; NON-TEMPORAL loads (zero-reuse stream,
// mark evict-first so L1/L2 insertion doesn't throttle the stream).
// Row (4096 f) covered in 4 phases of 256 float4; group of phase p for a
// thread is 2p + (tid>>7) — constant per wave -> static accumulators +
// shuffle reduce, no LDS in the hot loop.
// ---------------------------------------------------------------------------
__global__ __launch_bounds__(256) void k_reduce(const float* __restrict__ scores,
                                                double* __restrict__ partials) {
    const int bid   = blockIdx.x;        // [0, 2048)
    const int b     = bid >> 7;
    const int chunk = bid & 127;
    const int tid   = threadIdx.x;

    const f32x4* base = reinterpret_cast<const f32x4*>(
        scores + (size_t)b * T_DIM * D_DIM + (size_t)chunk * 16 * D_DIM);

    double a0 = 0.0, a1 = 0.0, a2 = 0.0, a3 = 0.0;
    #pragma unroll 4
    for (int r = 0; r < 16; ++r) {
        const f32x4* row = base + (size_t)r * (D_DIM / 4);
        const f32x4 v0 = __builtin_nontemporal_load(row + tid);
        const f32x4 v1 = __builtin_nontemporal_load(row + tid + 256);
        const f32x4 v2 = __builtin_nontemporal_load(row + tid + 512);
        const f32x4 v3 = __builtin_nontemporal_load(row + tid + 768);
        a0 += (double)v0.x + (double)v0.y + (double)v0.z + (double)v0.w;
        a1 += (double)v1.x + (double)v1.y + (double)v1.z + (double)v1.w;
        a2 += (double)v2.x + (double)v2.y + (double)v2.z + (double)v2.w;
        a3 += (double)v3.x + (double)v3.y + (double)v3.z + (double)v3.w;
    }

    // Per-wave reduce: within a wave, group of phase p is g = 2p + (wave>>1).
    const int lane = tid & 63;
    const int wave = tid >> 6;
    __shared__ double wsum[4][4];        // [wave][phase]
    double acc[4] = {a0, a1, a2, a3};
    #pragma unroll
    for (int p = 0; p < 4; ++p) {
        double v = acc[p];
        #pragma unroll
        for (int off = 32; off > 0; off >>= 1) v += __shfl_down(v, off, 64);
        if (lane == 0) wsum[wave][p] = v;
    }
    __syncthreads();

    if (tid < G_DIM) {
        // group g: phase p = g>>1, waves w0 = 2*(g&1), w0+1
        const int p  = tid >> 1;
        const int w0 = (tid & 1) * 2;
        partials[(size_t)(b * G_DIM + tid) * CHUNKS + chunk] = wsum[w0][p] + wsum[w0 + 1][p];
    }
}

// ---------------------------------------------------------------------------
// Shared MLP routine: given this b's 8 group means, run Linear->GELU->LN->
// Linear->(+gumbel)->softmax->alloc->clip->discretize. Outputs p[8], hard[8],
// bit_w[8][3], sum of p*log(p) and sum of hard. Pure function of inputs ->
// identical results wherever (re)computed, so redundant per-block evaluation
// is deterministic.
// ---------------------------------------------------------------------------
__device__ __forceinline__ void run_mlp(const float* __restrict__ gi8, int b,
                                        const float* __restrict__ u,
                                        const float* __restrict__ W1,
                                        const float* __restrict__ b1,
                                        const float* __restrict__ ln_g,
                                        const float* __restrict__ ln_b,
                                        const float* __restrict__ W2,
                                        const float* __restrict__ b2,
                                        float* __restrict__ p,      // [8]
                                        float* __restrict__ hard,   // [8]
                                        float (*bw)[3],             // [8][3]
                                        float* entb_out, float* bs_out) {
    float h[H_DIM];
    #pragma unroll
    for (int i = 0; i < H_DIM; ++i) {
        float a = b1[i];
        #pragma unroll
        for (int g = 0; g < G_DIM; ++g) a += gi8[g] * W1[g * H_DIM + i];
        h[i] = 0.5f * a * (1.0f + erff(a * 0.70710678118654752440f));
    }
    float mu = 0.f;
    #pragma unroll
    for (int i = 0; i < H_DIM; ++i) mu += h[i];
    mu *= (1.0f / (float)H_DIM);
    float var = 0.f;
    #pragma unroll
    for (int i = 0; i < H_DIM; ++i) { float d = h[i] - mu; var += d * d; }
    var *= (1.0f / (float)H_DIM);
    const float inv = rsqrtf(var + 1e-5f);
    #pragma unroll
    for (int i = 0; i < H_DIM; ++i) h[i] = (h[i] - mu) * inv * ln_g[i] + ln_b[i];

    float z[G_DIM];
    #pragma unroll
    for (int j = 0; j < G_DIM; ++j) {
        float a = b2[j];
        #pragma unroll
        for (int i = 0; i < H_DIM; ++i) a += h[i] * W2[i * G_DIM + j];
        const float uu = u[b * G_DIM + j];
        z[j] = a + (-logf(-logf(uu + 1e-8f) + 1e-8f));
    }
    float m = z[0];
    #pragma unroll
    for (int j = 1; j < G_DIM; ++j) m = fmaxf(m, z[j]);
    float ssum = 0.f;
    #pragma unroll
    for (int j = 0; j < G_DIM; ++j) { p[j] = expf(z[j] - m); ssum += p[j]; }
    const float rs = 1.0f / ssum;

    float alloc[G_DIM]; float asum = 0.f;
    #pragma unroll
    for (int j = 0; j < G_DIM; ++j) {
        p[j] *= rs;
        alloc[j] = 2.0f + p[j] * 6.0f;
        asum += alloc[j];
    }
    const float scale = 32.0f / asum;   // budget = 4 * 8

    float entb = 0.f, bs = 0.f;
    #pragma unroll
    for (int j = 0; j < G_DIM; ++j) {
        float a = alloc[j] * scale;
        a = fminf(fmaxf(a, 2.0f), 8.0f);
        // nearest of {2,4,8}; argmin tie-break -> lower index
        const float hd = (a <= 3.0f) ? 2.0f : ((a <= 6.0f) ? 4.0f : 8.0f);
        hard[j] = hd;
        entb += p[j] * logf(p[j] + 1e-8f);
        bs += hd;
        const float x0 = expf(-fabsf(hd - 2.0f));
        const float x1 = expf(-fabsf(hd - 4.0f));
        const float x2 = expf(-fabsf(hd - 8.0f));
        const float mm = fmaxf(x0, fmaxf(x1, x2));
        const float e0 = expf(x0 - mm), e1 = expf(x1 - mm), e2 = expf(x2 - mm);
        const float ir = 1.0f / (e0 + e1 + e2);
        bw[j][0] = e0 * ir;
        bw[j][1] = e1 * ir;
        bw[j][2] = e2 * ir;
    }
    *entb_out = entb;
    *bs_out = bs;
}

// ---------------------------------------------------------------------------
// Kernel 2 (fused tail): 64 blocks x 256 threads.
// Every block: reduce its own b's 1024 partials -> 8 group means (shuffle),
// thread 0 runs the MLP redundantly -> bit_w in LDS, then all 256 threads
// write one float4 of embeddings + group_indices.
// Block 0 additionally performs the full per-b MLP pass for all 16 b and
// writes discrete_bits, bit_probs, and the two scalars.
// ---------------------------------------------------------------------------
__global__ __launch_bounds__(256) void k_tail(const double* __restrict__ partials,
                                              const float* __restrict__ u,
                                              const float* __restrict__ W1,
                                              const float* __restrict__ b1,
                                              const float* __restrict__ ln_g,
                                              const float* __restrict__ ln_b,
                                              const float* __restrict__ W2,
                                              const float* __restrict__ b2,
                                              const float* __restrict__ emb,
                                              float* __restrict__ out) {
    const int blk = blockIdx.x;          // [0,64)
    const int b   = blk >> 2;
    const int q   = blk & 3;
    const int tid = threadIdx.x;

    __shared__ float s_gi[B_DIM * G_DIM];  // block0: all (b,g); others: [0..8)
    __shared__ float s_w[G_DIM][3];        // bit_w for this block's b
    __shared__ float s_ent[B_DIM], s_bs[B_DIM];

    if (blk == 0) {
        // --- full k_mlp replica: all-b group means ---
        if (tid < 128) {
            double s = 0.0;
            #pragma unroll 8
            for (int c = 0; c < CHUNKS; ++c) s += partials[(size_t)tid * CHUNKS + c];
            s_gi[tid] = (float)(s * (1.0 / ((double)T_DIM * (double)GS)));
        }
        __syncthreads();
        if (tid < B_DIM) {
            float p[G_DIM], hard[G_DIM], bw[G_DIM][3], entb, bs;
            run_mlp(&s_gi[tid * G_DIM], tid, u, W1, b1, ln_g, ln_b, W2, b2,
                    p, hard, bw, &entb, &bs);
            #pragma unroll
            for (int j = 0; j < G_DIM; ++j) {
                out[OUT_DBITS  + tid * G_DIM + j] = hard[j];
                out[OUT_BPROBS + tid * G_DIM + j] = p[j];
            }
            s_ent[tid] = entb;
            s_bs[tid]  = bs;
            if (tid == 0) {           // this block's b == 0
                #pragma unroll
                for (int j = 0; j < G_DIM; ++j) {
                    s_w[j][0] = bw[j][0]; s_w[j][1] = bw[j][1]; s_w[j][2] = bw[j][2];
                }
            }
        }
        __syncthreads();
        if (tid == 0) {
            float tb = 0.f, te = 0.f;
            #pragma unroll
            for (int bb = 0; bb < B_DIM; ++bb) { tb += s_bs[bb]; te += s_ent[bb]; }
            const float mb = tb * (1.0f / (float)(B_DIM * G_DIM));
            out[OUT_BLOSS] = (mb - 4.0f) * (mb - 4.0f);
            out[OUT_DIV]   = -te * (1.0f / (float)B_DIM);
        }
    } else {
        // --- own-b group means: 1024 doubles, 4 per thread, shuffle reduce ---
        const double* pb = partials + (size_t)b * G_DIM * CHUNKS;
        double v = 0.0;
        #pragma unroll
        for (int k = 0; k < 4; ++k) v += pb[tid * 4 + k];
        // threads [g*32, g*32+32) hold group g = tid>>5; width-32 reduce
        #pragma unroll
        for (int off = 16; off > 0; off >>= 1) v += __shfl_down(v, off, 32);
        if ((tid & 31) == 0)
            s_gi[tid >> 5] = (float)(v * (1.0 / ((double)T_DIM * (double)GS)));
        __syncthreads();
        if (tid == 0) {
            float p[G_DIM], hard[G_DIM], bw[G_DIM][3], entb, bs;
            run_mlp(&s_gi[0], b, u, W1, b1, ln_g, ln_b, W2, b2,
                    p, hard, bw, &entb, &bs);
            #pragma unroll
            for (int j = 0; j < G_DIM; ++j) {
                s_w[j][0] = bw[j][0]; s_w[j][1] = bw[j][1]; s_w[j][2] = bw[j][2];
            }
        }
    }
    __syncthreads();

    // --- embedding + group_indices write: one float4 each ---
    const int l  = blk * 256 + tid;       // [0,16384) float4 index
    const int g  = q * 2 + (tid >> 7);    // group within b
    const int j4 = tid & 127;

    const float4* e4 = reinterpret_cast<const float4*>(emb);  // [3][128]
    const float4 e0 = e4[0 * 128 + j4];
    const float4 e1 = e4[1 * 128 + j4];
    const float4 e2 = e4[2 * 128 + j4];
    const float w0 = s_w[g][0], w1 = s_w[g][1], w2 = s_w[g][2];

    float4 r;
    r.x = w0 * e0.x + w1 * e1.x + w2 * e2.x;
    r.y = w0 * e0.y + w1 * e1.y + w2 * e2.y;
    r.z = w0 * e0.z + w1 * e1.z + w2 * e2.z;
    r.w = w0 * e0.w + w1 * e1.w + w2 * e2.w;

    float4* o4 = reinterpret_cast<float4*>(out);
    o4[(OUT_EMB / 4) + l] = r;

    const float gv = (float)g;            // d // 512
    o4[(OUT_GIDX / 4) + l] = make_float4(gv, gv, gv, gv);
}

// ---------------------------------------------------------------------------
extern "C" void kernel_launch(void* const* d_in, const int* in_sizes, int n_in,
                              void* d_out, int out_size, void* d_ws, size_t ws_size,
                              hipStream_t stream) {
    const float* scores = (const float*)d_in[0];
    const float* u      = (const float*)d_in[1];
    const float* W1     = (const float*)d_in[2];
    const float* b1     = (const float*)d_in[3];
    const float* ln_g   = (const float*)d_in[4];
    const float* ln_b   = (const float*)d_in[5];
    const float* W2     = (const float*)d_in[6];
    const float* b2     = (const float*)d_in[7];
    const float* emb    = (const float*)d_in[8];
    float* out = (float*)d_out;

    double* partials = (double*)d_ws;     // 16384 * 8 B

    k_reduce<<<B_DIM * CHUNKS, 256, 0, stream>>>(scores, partials);
    k_tail<<<64, 256, 0, stream>>>(partials, u, W1, b1, ln_g, ln_b, W2, b2, emb, out);
}